// Round 2
// baseline (1553.743 us; speedup 1.0000x reference)
//
#include <hip/hip_runtime.h>
#include <hip/hip_bf16.h>

// MoE dense: E=8, D_IN=1024, D_HID=2048, D_OUT=1024, N=8192.
// bf16 MFMA GEMMs (m97 128x128 structure), fp32 gate + combine.
// ws-size-adaptive: batched tier (all weights converted once, z=8 GEMMs,
// N-chunked h buffers) or per-expert tier (weight scratch reused, gate-
// weighted fp32 RMW fused into layer-3 epilogue).

typedef short s16x8 __attribute__((ext_vector_type(8)));
typedef float f32x4 __attribute__((ext_vector_type(4)));

#define E_ 8
#define DIN_ 1024
#define DH_ 2048
#define DOUT_ 1024
#define NTOK_ 8192

__device__ __forceinline__ unsigned short f2bf(float x) {
    union { float f; unsigned u; } c; c.f = x;
    unsigned r = c.u + 0x7fffu + ((c.u >> 16) & 1u);   // RNE
    return (unsigned short)(r >> 16);
}
__device__ __forceinline__ float bf2f(unsigned short s) {
    union { unsigned u; float f; } c; c.u = ((unsigned)s) << 16;
    return c.f;
}
__device__ __forceinline__ void gload_lds16(const void* g, void* l) {
    __builtin_amdgcn_global_load_lds((const __attribute__((address_space(1))) void*)g,
                                     (__attribute__((address_space(3))) void*)l, 16, 0, 0);
}

// ---------------- fp32 -> bf16 elementwise (x) ----------------
__global__ __launch_bounds__(256) void cvt_f32_bf16(const float* __restrict__ in,
                                                    unsigned short* __restrict__ out,
                                                    long n8) {
    long i = (long)blockIdx.x * 256 + threadIdx.x;
    if (i >= n8) return;
    const float4* p = (const float4*)(in + i * 8);
    float4 a = p[0], b = p[1];
    s16x8 v;
    v[0] = (short)f2bf(a.x); v[1] = (short)f2bf(a.y);
    v[2] = (short)f2bf(a.z); v[3] = (short)f2bf(a.w);
    v[4] = (short)f2bf(b.x); v[5] = (short)f2bf(b.y);
    v[6] = (short)f2bf(b.z); v[7] = (short)f2bf(b.w);
    *(s16x8*)(out + i * 8) = v;
}

// ------------- transpose+convert: in [Z][K][Nn] fp32 -> out [Z][Nn][K] bf16 -------------
__global__ __launch_bounds__(256) void tcvt_kernel(const float* __restrict__ in,
                                                   unsigned short* __restrict__ out,
                                                   int K, int Nn) {
    __shared__ unsigned short t[64][72];
    const int e = blockIdx.z;
    const float* ie = in + (long)e * K * Nn;
    unsigned short* oe = out + (long)e * K * Nn;
    const int k0 = blockIdx.y * 64, n0 = blockIdx.x * 64;
    const int tid = threadIdx.x;
    const int c4 = (tid & 15) * 4;
#pragma unroll
    for (int i = 0; i < 4; ++i) {
        const int k = (tid >> 4) + 16 * i;
        float4 v = *(const float4*)(ie + (long)(k0 + k) * Nn + n0 + c4);
        t[c4 + 0][k] = f2bf(v.x);
        t[c4 + 1][k] = f2bf(v.y);
        t[c4 + 2][k] = f2bf(v.z);
        t[c4 + 3][k] = f2bf(v.w);
    }
    __syncthreads();
#pragma unroll
    for (int i = 0; i < 2; ++i) {
        const int idx = tid + 256 * i;
        const int rn = idx >> 3, ck = idx & 7;
        s16x8 v = *(const s16x8*)&t[rn][ck * 8];
        *(s16x8*)(oe + (long)(n0 + rn) * K + k0 + ck * 8) = v;
    }
}

// ---------------- gate: softmax(x @ gW + gb) , fp32 ----------------
__global__ __launch_bounds__(256) void gate_kernel(const float* __restrict__ x,
                                                   const float* __restrict__ gW,
                                                   const float* __restrict__ gb,
                                                   float* __restrict__ gate) {
    __shared__ float gws[8 * 1024];        // transposed [e][k]
    const int tid = threadIdx.x;
    for (int idx = tid; idx < 8 * 1024; idx += 256)
        gws[(idx & 7) * 1024 + (idx >> 3)] = gW[idx];
    __syncthreads();
    const int w = tid >> 6, l = tid & 63;
    const int n = blockIdx.x * 4 + w;
    const float* xr = x + (long)n * 1024;
    float acc[8] = {};
    for (int k = l; k < 1024; k += 64) {
        const float xv = xr[k];
#pragma unroll
        for (int e = 0; e < 8; ++e) acc[e] += xv * gws[e * 1024 + k];
    }
#pragma unroll
    for (int e = 0; e < 8; ++e)
        for (int off = 32; off > 0; off >>= 1) acc[e] += __shfl_xor(acc[e], off);
    if (l == 0) {
        float m = -1e30f;
#pragma unroll
        for (int e = 0; e < 8; ++e) { acc[e] += gb[e]; m = fmaxf(m, acc[e]); }
        float s = 0.f;
#pragma unroll
        for (int e = 0; e < 8; ++e) { acc[e] = __expf(acc[e] - m); s += acc[e]; }
        const float inv = 1.0f / s;
#pragma unroll
        for (int e = 0; e < 8; ++e) gate[n * 8 + e] = acc[e] * inv;
    }
}

// ---------------- batched bf16 GEMM ----------------
// FUSE=0: out bf16 [z][M][Nn] = act(A[z] @ Bt[z]^T + bias[z])
// FUSE=1: out fp32 [M][Nn] (+)= gate8[row*8] * (A @ Bt^T + bias)   (z must be 1)
template <int FUSE>
__global__ __launch_bounds__(256) void moe_gemm(const unsigned short* __restrict__ A,
                                                const unsigned short* __restrict__ Bt,
                                                const float* __restrict__ bias,
                                                void* __restrict__ outp,
                                                const float* __restrict__ gate8,
                                                int M, int Nn, int K,
                                                long strideAe, long strideBe, long strideOe,
                                                int relu, int first) {
    __shared__ __align__(16) char smem[34816];
    const int tid = threadIdx.x;
    const int w = tid >> 6, l = tid & 63;
    const int e = blockIdx.z;
    const int m0 = blockIdx.y * 128;
    const int n0 = blockIdx.x * 128;

    const unsigned short* Ae = A + (long)e * strideAe;
    const unsigned short* Be = Bt + (long)e * strideBe;

    const int srow = tid >> 2;
    const int scol = (tid & 3) * 8;
    const unsigned short* gA = Ae + (long)(m0 + srow) * K + scol;
    const unsigned short* gB = Be + (long)(n0 + srow) * K + scol;
    const long rstep = (long)64 * K;

    char* ldsAw = smem + w * 1024;
    char* ldsBw = smem + 8192 + w * 1024;

    const int wr = w >> 1, wc = w & 1;
    const int lr = l & 15;
    const int aoff = (64 * wr + lr) * 64 + (l >> 4) * 16;
    const int boff = 8192 + (64 * wc + lr) * 64 + (l >> 4) * 16;

    f32x4 acc[4][4] = {};
    const int nt = K >> 5;

    gload_lds16(gA, ldsAw);
    gload_lds16(gA + rstep, ldsAw + 4096);
    gload_lds16(gB, ldsBw);
    gload_lds16(gB + rstep, ldsBw + 4096);
    __syncthreads();

    int cur = 0;
    for (int t = 0; t < nt; ++t) {
        if (t + 1 < nt) {
            const int nb = (cur ^ 1) * 16384;
            const unsigned short* a = gA + (t + 1) * 32;
            const unsigned short* b = gB + (t + 1) * 32;
            gload_lds16(a, ldsAw + nb);
            gload_lds16(a + rstep, ldsAw + nb + 4096);
            gload_lds16(b, ldsBw + nb);
            gload_lds16(b + rstep, ldsBw + nb + 4096);
        }
        const char* buf = smem + cur * 16384;
        s16x8 af[4], bfr[4];
#pragma unroll
        for (int m = 0; m < 4; ++m) af[m] = *(const s16x8*)(buf + aoff + m * 1024);
#pragma unroll
        for (int n = 0; n < 4; ++n) bfr[n] = *(const s16x8*)(buf + boff + n * 1024);
#pragma unroll
        for (int m = 0; m < 4; ++m)
#pragma unroll
            for (int n = 0; n < 4; ++n)
                acc[m][n] = __builtin_amdgcn_mfma_f32_16x16x32_bf16(af[m], bfr[n], acc[m][n], 0, 0, 0);
        __syncthreads();
        cur ^= 1;
    }

    const float* be = bias + (long)e * Nn;

    if constexpr (!FUSE) {
        // bias (+relu) -> bf16, repack via LDS for coalesced 16B stores
        unsigned short (*h)[136] = (unsigned short (*)[136])smem;
#pragma unroll
        for (int n = 0; n < 4; ++n) {
            const int lc = 64 * wc + 16 * n + lr;
            const float bb = be[n0 + lc];
#pragma unroll
            for (int m = 0; m < 4; ++m) {
                const int rbase = 64 * wr + 16 * m + (l >> 4) * 4;
                f32x4 v = acc[m][n];
#pragma unroll
                for (int j = 0; j < 4; ++j) {
                    float xv = v[j] + bb;
                    if (relu) xv = fmaxf(xv, 0.0f);
                    h[rbase + j][lc] = f2bf(xv);
                }
            }
        }
        __syncthreads();
        unsigned short* oe = (unsigned short*)outp + (long)e * strideOe;
#pragma unroll
        for (int it = 0; it < 8; ++it) {
            const int row = (tid >> 4) + 16 * it;
            const int ch = tid & 15;
            s16x8 v = *(const s16x8*)&h[row][ch * 8];
            *(s16x8*)(oe + (long)(m0 + row) * Nn + n0 + ch * 8) = v;
        }
    } else {
        // fp32 gate-weighted RMW into out, two 64-row passes through LDS
        float* outf = (float*)outp;
        float (*h2)[132] = (float (*)[132])smem;   // 64*132*4 = 33792 B
#pragma unroll
        for (int p2 = 0; p2 < 2; ++p2) {
            if (p2) __syncthreads();
            if (wr == p2) {
#pragma unroll
                for (int n = 0; n < 4; ++n) {
                    const int lc = 64 * wc + 16 * n + lr;
                    const float bb = be[n0 + lc];
#pragma unroll
                    for (int m = 0; m < 4; ++m) {
                        const int rloc = 16 * m + (l >> 4) * 4;
                        f32x4 v = acc[m][n];
#pragma unroll
                        for (int j = 0; j < 4; ++j) h2[rloc + j][lc] = v[j] + bb;
                    }
                }
            }
            __syncthreads();
#pragma unroll
            for (int it = 0; it < 8; ++it) {
                const int lin = it * 256 + tid;
                const int row = lin >> 5;            // 0..63
                const int c4 = (lin & 31) * 4;       // 0..124
                const long grow = (long)m0 + p2 * 64 + row;
                const float g = gate8[grow * 8];
                float* op = outf + grow * Nn + n0 + c4;
                float4 hv = *(const float4*)&h2[row][c4];
                float4 r;
                if (first) {
                    r = make_float4(g * hv.x, g * hv.y, g * hv.z, g * hv.w);
                } else {
                    float4 o0 = *(const float4*)op;
                    r = make_float4(o0.x + g * hv.x, o0.y + g * hv.y,
                                    o0.z + g * hv.z, o0.w + g * hv.w);
                }
                *(float4*)op = r;
            }
        }
    }
}

// ---------------- combine (batched tier): out[n][c] = sum_e gate[n][e]*o_e[n][c] ----------------
__global__ __launch_bounds__(256) void combine_kernel(const unsigned short* __restrict__ o,
                                                      const float* __restrict__ gate,
                                                      float* __restrict__ out, int Nc) {
    const long t = (long)blockIdx.x * 256 + threadIdx.x;
    const int n = (int)(t >> 7);
    const int ch = (int)(t & 127) * 8;
    float g[8];
#pragma unroll
    for (int e = 0; e < 8; ++e) g[e] = gate[n * 8 + e];
    float a[8] = {};
#pragma unroll
    for (int e = 0; e < 8; ++e) {
        s16x8 v = *(const s16x8*)(o + (long)e * Nc * DOUT_ + (long)n * DOUT_ + ch);
        const float ge = g[e];
#pragma unroll
        for (int j = 0; j < 8; ++j) a[j] = fmaf(ge, bf2f((unsigned short)v[j]), a[j]);
    }
    float* op = out + (long)n * DOUT_ + ch;
    *(float4*)(op) = make_float4(a[0], a[1], a[2], a[3]);
    *(float4*)(op + 4) = make_float4(a[4], a[5], a[6], a[7]);
}

extern "C" void kernel_launch(void* const* d_in, const int* in_sizes, int n_in,
                              void* d_out, int out_size, void* d_ws, size_t ws_size,
                              hipStream_t stream) {
    const float* x   = (const float*)d_in[0];
    const float* gW  = (const float*)d_in[1];
    const float* gb  = (const float*)d_in[2];
    const float* W0  = (const float*)d_in[3];
    const float* b0  = (const float*)d_in[4];
    const float* W1  = (const float*)d_in[5];
    const float* b1  = (const float*)d_in[6];
    const float* Wf  = (const float*)d_in[7];
    const float* bfb = (const float*)d_in[8];
    float* out = (float*)d_out;
    char* ws = (char*)d_ws;

    // mandatory buffers
    unsigned short* xb = (unsigned short*)ws;                       // 16 MiB
    float* gate = (float*)(ws + (size_t)NTOK_ * DIN_ * 2);          // 256 KiB
    const size_t base = (size_t)NTOK_ * DIN_ * 2 + (size_t)NTOK_ * E_ * 4;

    const size_t wfull = (size_t)E_ * 2 * ((size_t)DIN_ * DH_ + (size_t)DH_ * DH_ + (size_t)DH_ * DOUT_); // 128 MiB
    const size_t wexp = wfull / E_;                                                                        // 16 MiB

    // tier select from ws_size
    int Nc = 0, batched = 0;
    if (ws_size > base + wfull) {
        const size_t rem = ws_size - base - wfull;
        for (int nc = 8192; nc >= 128; nc >>= 1)
            if ((size_t)nc * 65536 <= rem) { Nc = nc; batched = 1; break; }   // 2 bufs * E * Nc * DH * 2B
    }
    if (!batched) {
        const size_t rem = (ws_size > base + wexp) ? ws_size - base - wexp : 0;
        for (int nc = 8192; nc >= 128; nc >>= 1)
            if ((size_t)nc * 8192 <= rem) { Nc = nc; break; }                 // 2 bufs * Nc * DH * 2B
        if (!Nc) Nc = 128;  // last resort
    }
    const int nch = NTOK_ / Nc;

    cvt_f32_bf16<<<NTOK_ * DIN_ / 8 / 256, 256, 0, stream>>>(x, xb, (long)NTOK_ * DIN_ / 8);
    gate_kernel<<<NTOK_ / 4, 256, 0, stream>>>(x, gW, gb, gate);

    if (batched) {
        unsigned short* W0b = (unsigned short*)(ws + base);
        unsigned short* W1b = W0b + (size_t)E_ * DIN_ * DH_;
        unsigned short* Wfb = W1b + (size_t)E_ * DH_ * DH_;
        unsigned short* h0  = Wfb + (size_t)E_ * DH_ * DOUT_;
        unsigned short* h1  = h0 + (size_t)E_ * Nc * DH_;
        tcvt_kernel<<<dim3(DH_ / 64, DIN_ / 64, E_), 256, 0, stream>>>(W0, W0b, DIN_, DH_);
        tcvt_kernel<<<dim3(DH_ / 64, DH_ / 64, E_), 256, 0, stream>>>(W1, W1b, DH_, DH_);
        tcvt_kernel<<<dim3(DOUT_ / 64, DH_ / 64, E_), 256, 0, stream>>>(Wf, Wfb, DH_, DOUT_);
        for (int c = 0; c < nch; ++c) {
            const long r0 = (long)c * Nc;
            moe_gemm<0><<<dim3(DH_ / 128, Nc / 128, E_), 256, 0, stream>>>(
                xb + r0 * DIN_, W0b, b0, h0, nullptr, Nc, DH_, DIN_,
                0L, (long)DIN_ * DH_, (long)Nc * DH_, 1, 0);
            moe_gemm<0><<<dim3(DH_ / 128, Nc / 128, E_), 256, 0, stream>>>(
                h0, W1b, b1, h1, nullptr, Nc, DH_, DH_,
                (long)Nc * DH_, (long)DH_ * DH_, (long)Nc * DH_, 1, 0);
            unsigned short* o = h0;  // h0 chunk dead after L2; o needs half its bytes
            moe_gemm<0><<<dim3(DOUT_ / 128, Nc / 128, E_), 256, 0, stream>>>(
                h1, Wfb, bfb, o, nullptr, Nc, DOUT_, DH_,
                (long)Nc * DH_, (long)DH_ * DOUT_, (long)Nc * DOUT_, 0, 0);
            combine_kernel<<<Nc / 2, 256, 0, stream>>>(o, gate + r0 * E_, out + r0 * DOUT_, Nc);
        }
    } else {
        unsigned short* W0s = (unsigned short*)(ws + base);
        unsigned short* W1s = W0s + (size_t)DIN_ * DH_;
        unsigned short* Wfs = W1s + (size_t)DH_ * DH_;
        unsigned short* h0s = Wfs + (size_t)DH_ * DOUT_;
        unsigned short* h1s = h0s + (size_t)Nc * DH_;
        for (int e = 0; e < E_; ++e) {
            tcvt_kernel<<<dim3(DH_ / 64, DIN_ / 64, 1), 256, 0, stream>>>(
                W0 + (size_t)e * DIN_ * DH_, W0s, DIN_, DH_);
            tcvt_kernel<<<dim3(DH_ / 64, DH_ / 64, 1), 256, 0, stream>>>(
                W1 + (size_t)e * DH_ * DH_, W1s, DH_, DH_);
            tcvt_kernel<<<dim3(DOUT_ / 64, DH_ / 64, 1), 256, 0, stream>>>(
                Wf + (size_t)e * DH_ * DOUT_, Wfs, DH_, DOUT_);
            for (int c = 0; c < nch; ++c) {
                const long r0 = (long)c * Nc;
                moe_gemm<0><<<dim3(DH_ / 128, Nc / 128, 1), 256, 0, stream>>>(
                    xb + r0 * DIN_, W0s, b0 + e * DH_, h0s, nullptr, Nc, DH_, DIN_,
                    0L, 0L, 0L, 1, 0);
                moe_gemm<0><<<dim3(DH_ / 128, Nc / 128, 1), 256, 0, stream>>>(
                    h0s, W1s, b1 + e * DH_, h1s, nullptr, Nc, DH_, DH_,
                    0L, 0L, 0L, 1, 0);
                moe_gemm<1><<<dim3(DOUT_ / 128, Nc / 128, 1), 256, 0, stream>>>(
                    h1s, Wfs, bfb + e * DOUT_, out + r0 * DOUT_, gate + r0 * E_ + e,
                    Nc, DOUT_, DH_, 0L, 0L, 0L, 0, (e == 0) ? 1 : 0);
            }
        }
    }
}

// Round 3
// 1144.465 us; speedup vs baseline: 1.3576x; 1.3576x over previous
//
#include <hip/hip_runtime.h>
#include <hip/hip_bf16.h>

// MoE dense: E=8, D_IN=1024, D_HID=2048, D_OUT=1024, N=8192.
// bf16 MFMA GEMMs; batched tier uses 256x256 8-phase template (T2+T3+T4+T5),
// per-expert fallback tier keeps the 128x128 m97 structure.

typedef short s16x8 __attribute__((ext_vector_type(8)));
typedef float f32x4 __attribute__((ext_vector_type(4)));

#define E_ 8
#define DIN_ 1024
#define DH_ 2048
#define DOUT_ 1024
#define NTOK_ 8192

__device__ __forceinline__ unsigned short f2bf(float x) {
    union { float f; unsigned u; } c; c.f = x;
    unsigned r = c.u + 0x7fffu + ((c.u >> 16) & 1u);   // RNE
    return (unsigned short)(r >> 16);
}
__device__ __forceinline__ float bf2f(unsigned short s) {
    union { unsigned u; float f; } c; c.u = ((unsigned)s) << 16;
    return c.f;
}
__device__ __forceinline__ void gload_lds16(const void* g, void* l) {
    __builtin_amdgcn_global_load_lds((const __attribute__((address_space(1))) void*)g,
                                     (__attribute__((address_space(3))) void*)l, 16, 0, 0);
}

// ---------------- fp32 -> bf16 elementwise (x) ----------------
__global__ __launch_bounds__(256) void cvt_f32_bf16(const float* __restrict__ in,
                                                    unsigned short* __restrict__ out,
                                                    long n8) {
    long i = (long)blockIdx.x * 256 + threadIdx.x;
    if (i >= n8) return;
    const float4* p = (const float4*)(in + i * 8);
    float4 a = p[0], b = p[1];
    s16x8 v;
    v[0] = (short)f2bf(a.x); v[1] = (short)f2bf(a.y);
    v[2] = (short)f2bf(a.z); v[3] = (short)f2bf(a.w);
    v[4] = (short)f2bf(b.x); v[5] = (short)f2bf(b.y);
    v[6] = (short)f2bf(b.z); v[7] = (short)f2bf(b.w);
    *(s16x8*)(out + i * 8) = v;
}

// ------------- transpose+convert: in [Z][K][Nn] fp32 -> out [Z][Nn][K] bf16 -------------
__global__ __launch_bounds__(256) void tcvt_kernel(const float* __restrict__ in,
                                                   unsigned short* __restrict__ out,
                                                   int K, int Nn) {
    __shared__ unsigned short t[64][72];
    const int e = blockIdx.z;
    const float* ie = in + (long)e * K * Nn;
    unsigned short* oe = out + (long)e * K * Nn;
    const int k0 = blockIdx.y * 64, n0 = blockIdx.x * 64;
    const int tid = threadIdx.x;
    const int c4 = (tid & 15) * 4;
#pragma unroll
    for (int i = 0; i < 4; ++i) {
        const int k = (tid >> 4) + 16 * i;
        float4 v = *(const float4*)(ie + (long)(k0 + k) * Nn + n0 + c4);
        t[c4 + 0][k] = f2bf(v.x);
        t[c4 + 1][k] = f2bf(v.y);
        t[c4 + 2][k] = f2bf(v.z);
        t[c4 + 3][k] = f2bf(v.w);
    }
    __syncthreads();
#pragma unroll
    for (int i = 0; i < 2; ++i) {
        const int idx = tid + 256 * i;
        const int rn = idx >> 3, ck = idx & 7;
        s16x8 v = *(const s16x8*)&t[rn][ck * 8];
        *(s16x8*)(oe + (long)(n0 + rn) * K + k0 + ck * 8) = v;
    }
}

// ---------------- gate: softmax(x @ gW + gb) , fp32 ----------------
__global__ __launch_bounds__(256) void gate_kernel(const float* __restrict__ x,
                                                   const float* __restrict__ gW,
                                                   const float* __restrict__ gb,
                                                   float* __restrict__ gate) {
    __shared__ float gws[8 * 1024];
    const int tid = threadIdx.x;
    for (int idx = tid; idx < 8 * 1024; idx += 256)
        gws[(idx & 7) * 1024 + (idx >> 3)] = gW[idx];
    __syncthreads();
    const int w = tid >> 6, l = tid & 63;
    const int n = blockIdx.x * 4 + w;
    const float* xr = x + (long)n * 1024;
    float acc[8] = {};
    for (int k = l; k < 1024; k += 64) {
        const float xv = xr[k];
#pragma unroll
        for (int e = 0; e < 8; ++e) acc[e] += xv * gws[e * 1024 + k];
    }
#pragma unroll
    for (int e = 0; e < 8; ++e)
        for (int off = 32; off > 0; off >>= 1) acc[e] += __shfl_xor(acc[e], off);
    if (l == 0) {
        float m = -1e30f;
#pragma unroll
        for (int e = 0; e < 8; ++e) { acc[e] += gb[e]; m = fmaxf(m, acc[e]); }
        float s = 0.f;
#pragma unroll
        for (int e = 0; e < 8; ++e) { acc[e] = __expf(acc[e] - m); s += acc[e]; }
        const float inv = 1.0f / s;
#pragma unroll
        for (int e = 0; e < 8; ++e) gate[n * 8 + e] = acc[e] * inv;
    }
}

// ================= 256x256 8-phase bf16 GEMM (batched tier) =================
// A [z][M][K], Bt [z][Nn][K] bf16 ; out bf16 [z][M][Nn] = act(A@Bt^T + bias)
// 512 thr = 8 waves (2Mx4N); BK=64; LDS 128KB = 2 K-tile dbuf (A 32K + B 32K).
// Swizzle: 16B chunk at phys slot s of row r holds logical chunk s^(r&7)
// (applied on global src for linear global_load_lds, and on ds_read addr).

#define BARR() asm volatile("s_barrier" ::: "memory")
#define LGKM0() do { asm volatile("s_waitcnt lgkmcnt(0)" ::: "memory"); \
                     __builtin_amdgcn_sched_barrier(0); } while (0)
#define VMW(n) do { asm volatile("s_waitcnt vmcnt(" #n ")" ::: "memory"); \
                    __builtin_amdgcn_sched_barrier(0); } while (0)

__global__ __launch_bounds__(512, 2) void moe_gemm256(const unsigned short* __restrict__ A,
                                                      const unsigned short* __restrict__ Bt,
                                                      const float* __restrict__ bias,
                                                      unsigned short* __restrict__ out,
                                                      int M, int Nn, int K,
                                                      long sAe, long sBe, long sOe, int relu) {
    extern __shared__ char smem[];
    const int tid = threadIdx.x;
    const int l = tid & 63, wid = tid >> 6;
    const int wr = wid >> 2, wc = wid & 3;
    const int e = blockIdx.z;
    // bijective XCD swizzle (m204) on the per-expert (x,y) grid
    const int gx = gridDim.x;
    int lin = blockIdx.x + gx * blockIdx.y;
    {
        const int nwg = gx * gridDim.y;
        const int q = nwg >> 3, r = nwg & 7;
        const int xcd = lin & 7, idx = lin >> 3;
        lin = (xcd < r ? xcd * (q + 1) : r * (q + 1) + (xcd - r) * q) + idx;
    }
    const int n0 = (lin % gx) * 256;
    const int m0 = (lin / gx) * 256;

    const unsigned short* Ae = A + (long)e * sAe;
    const unsigned short* Be = Bt + (long)e * sBe;

    // staging addresses: phys chunk (row, s=lane&7) <- logical c16 = s ^ (row&7)
    const int srow = wid * 8 + (l >> 3);
    const int sc8 = ((l & 7) ^ (l >> 3)) * 8;
    const unsigned short* pA = Ae + (long)(m0 + srow) * K + sc8;
    const unsigned short* pB = Be + (long)(n0 + srow) * K + sc8;
    const long kst64 = 64L * K;
    char* ldsW = smem + wid * 1024;

#define STAGE_A(buf, half, kt) do { \
        const unsigned short* s_ = pA + (long)(half) * 128 * K + (long)(kt) * 64; \
        char* d_ = ldsW + (buf) * 65536 + (half) * 16384; \
        gload_lds16(s_, d_); gload_lds16(s_ + kst64, d_ + 8192); } while (0)
#define STAGE_B(buf, half, kt) do { \
        const unsigned short* s_ = pB + (long)(half) * 128 * K + (long)(kt) * 64; \
        char* d_ = ldsW + (buf) * 65536 + 32768 + (half) * 16384; \
        gload_lds16(s_, d_); gload_lds16(s_ + kst64, d_ + 8192); } while (0)

    // ds_read fragment addressing
    const int arow = l & 15;
    const int aswz = ((l >> 4) ^ (l & 7)) << 4;
    const int aoffb = wr * 16384 + arow * 128;
    const int boffb = 32768 + wc * 8192 + arow * 128;

    f32x4 acc[8][4] = {};
    s16x8 af[4][2], bf0[2][2], bf1[2][2];

#define LDA(buf, mhalf) do { \
        const char* p_ = smem + (buf) * 65536 + aoffb + (mhalf) * 8192; \
        _Pragma("unroll") for (int mi_ = 0; mi_ < 4; ++mi_) \
        _Pragma("unroll") for (int kk_ = 0; kk_ < 2; ++kk_) \
            af[mi_][kk_] = *(const s16x8*)(p_ + mi_ * 2048 + (aswz ^ (kk_ << 6))); } while (0)
#define LDB(buf, nhalf, dst) do { \
        const char* p_ = smem + (buf) * 65536 + boffb + (nhalf) * 4096; \
        _Pragma("unroll") for (int ni_ = 0; ni_ < 2; ++ni_) \
        _Pragma("unroll") for (int kk_ = 0; kk_ < 2; ++kk_) \
            dst[ni_][kk_] = *(const s16x8*)(p_ + ni_ * 2048 + (aswz ^ (kk_ << 6))); } while (0)
#define MFMA8(mb, nb, bfr) do { __builtin_amdgcn_s_setprio(1); \
        _Pragma("unroll") for (int mi_ = 0; mi_ < 4; ++mi_) \
        _Pragma("unroll") for (int ni_ = 0; ni_ < 2; ++ni_) \
        _Pragma("unroll") for (int kk_ = 0; kk_ < 2; ++kk_) \
            acc[(mb) + mi_][(nb) + ni_] = __builtin_amdgcn_mfma_f32_16x16x32_bf16( \
                af[mi_][kk_], bfr[ni_][kk_], acc[(mb) + mi_][(nb) + ni_], 0, 0, 0); \
        __builtin_amdgcn_s_setprio(0); } while (0)

    const int nit = K >> 7;   // K/128, >=2 for all layers

    // prologue: X(kt0) full, then Y(kt1).B0, Y(kt1).A0
    STAGE_A(0, 0, 0); STAGE_A(0, 1, 0); STAGE_B(0, 0, 0); STAGE_B(0, 1, 0);
    STAGE_B(1, 0, 1); STAGE_A(1, 0, 1);
    VMW(4); BARR();

    for (int it = 0; it < nit; ++it) {
        const int ktY = 2 * it + 1;
        const int ktX2 = (it + 1 < nit) ? 2 * it + 2 : 0;
        const int ktY2 = (it + 1 < nit) ? 2 * it + 3 : 1;
        // ph1: compute X q(0,0); stage Y.A1
        LDA(0, 0); LDB(0, 0, bf0);
        STAGE_A(1, 1, ktY);
        BARR(); LGKM0(); MFMA8(0, 0, bf0); BARR();
        // ph2: X q(0,2); stage Y.B1
        LDB(0, 1, bf1);
        STAGE_B(1, 1, ktY);
        BARR(); LGKM0(); MFMA8(0, 2, bf1); BARR();
        // ph3: X q(4,2); stage X'.B0 (X B-halves free after ph2)
        LDA(0, 1);
        STAGE_B(0, 0, ktX2);
        BARR(); LGKM0(); MFMA8(4, 2, bf1); BARR();
        // ph4: X q(4,0); stage X'.B1; vmcnt -> Y fully landed
        STAGE_B(0, 1, ktX2);
        BARR(); MFMA8(4, 0, bf0); VMW(4); BARR();
        // ph5: compute Y q(0,0); stage X'.A0 (X A-halves free after ph3)
        LDA(1, 0); LDB(1, 0, bf0);
        STAGE_A(0, 0, ktX2);
        BARR(); LGKM0(); MFMA8(0, 0, bf0); BARR();
        // ph6: Y q(0,2); stage X'.A1
        LDB(1, 1, bf1);
        STAGE_A(0, 1, ktX2);
        BARR(); LGKM0(); MFMA8(0, 2, bf1); BARR();
        // ph7: Y q(4,2); stage Y'.B0 (Y B free after ph6)
        LDA(1, 1);
        STAGE_B(1, 0, ktY2);
        BARR(); LGKM0(); MFMA8(4, 2, bf1); BARR();
        // ph8: Y q(4,0); stage Y'.A0 (Y A free after ph7); vmcnt -> X' landed
        STAGE_A(1, 0, ktY2);
        BARR(); MFMA8(4, 0, bf0); VMW(4); BARR();
    }
    VMW(0); BARR();   // drain leftover stages before LDS reuse

    // epilogue: bias(+relu) -> bf16, two 128-row passes through LDS [128][272]
    unsigned short* oe = out + (long)e * sOe;
    const float* be = bias + (long)e * Nn;
    float bv[4];
#pragma unroll
    for (int ni = 0; ni < 4; ++ni) bv[ni] = be[n0 + 64 * wc + 16 * ni + arow];
    unsigned short (*h)[272] = (unsigned short (*)[272])smem;
#pragma unroll
    for (int p = 0; p < 2; ++p) {
        if (p) BARR();
        if (wr == p) {
#pragma unroll
            for (int mi = 0; mi < 8; ++mi)
#pragma unroll
                for (int ni = 0; ni < 4; ++ni) {
                    const int col = 64 * wc + 16 * ni + arow;
                    const int rl = 16 * mi + (l >> 4) * 4;
#pragma unroll
                    for (int j = 0; j < 4; ++j) {
                        float xv = acc[mi][ni][j] + bv[ni];
                        if (relu) xv = fmaxf(xv, 0.0f);
                        h[rl + j][col] = f2bf(xv);
                    }
                }
        }
        BARR();
#pragma unroll
        for (int i = 0; i < 8; ++i) {
            const int lin2 = i * 512 + tid;
            const int row = lin2 >> 5, ch = (lin2 & 31) * 8;
            s16x8 v = *(const s16x8*)&h[row][ch];
            *(s16x8*)(oe + (long)(m0 + 128 * p + row) * Nn + n0 + ch) = v;
        }
    }
#undef STAGE_A
#undef STAGE_B
#undef LDA
#undef LDB
#undef MFMA8
}

// ================= 128x128 GEMM (fallback tier) =================
// FUSE=0: out bf16 = act(A@Bt^T+bias); FUSE=1: out fp32 (+)= gate8 * (...)
template <int FUSE>
__global__ __launch_bounds__(256) void moe_gemm(const unsigned short* __restrict__ A,
                                                const unsigned short* __restrict__ Bt,
                                                const float* __restrict__ bias,
                                                void* __restrict__ outp,
                                                const float* __restrict__ gate8,
                                                int M, int Nn, int K,
                                                long strideAe, long strideBe, long strideOe,
                                                int relu, int first) {
    __shared__ __align__(16) char smem[34816];
    const int tid = threadIdx.x;
    const int w = tid >> 6, l = tid & 63;
    const int e = blockIdx.z;
    const int m0 = blockIdx.y * 128;
    const int n0 = blockIdx.x * 128;

    const unsigned short* Ae = A + (long)e * strideAe;
    const unsigned short* Be = Bt + (long)e * strideBe;

    const int srow = tid >> 2;
    const int scol = (tid & 3) * 8;
    const unsigned short* gA = Ae + (long)(m0 + srow) * K + scol;
    const unsigned short* gB = Be + (long)(n0 + srow) * K + scol;
    const long rstep = (long)64 * K;

    char* ldsAw = smem + w * 1024;
    char* ldsBw = smem + 8192 + w * 1024;

    const int wr = w >> 1, wc = w & 1;
    const int lr = l & 15;
    const int aoff = (64 * wr + lr) * 64 + (l >> 4) * 16;
    const int boff = 8192 + (64 * wc + lr) * 64 + (l >> 4) * 16;

    f32x4 acc[4][4] = {};
    const int nt = K >> 5;

    gload_lds16(gA, ldsAw);
    gload_lds16(gA + rstep, ldsAw + 4096);
    gload_lds16(gB, ldsBw);
    gload_lds16(gB + rstep, ldsBw + 4096);
    __syncthreads();

    int cur = 0;
    for (int t = 0; t < nt; ++t) {
        if (t + 1 < nt) {
            const int nb = (cur ^ 1) * 16384;
            const unsigned short* a = gA + (t + 1) * 32;
            const unsigned short* b = gB + (t + 1) * 32;
            gload_lds16(a, ldsAw + nb);
            gload_lds16(a + rstep, ldsAw + nb + 4096);
            gload_lds16(b, ldsBw + nb);
            gload_lds16(b + rstep, ldsBw + nb + 4096);
        }
        const char* buf = smem + cur * 16384;
        s16x8 af[4], bfr[4];
#pragma unroll
        for (int m = 0; m < 4; ++m) af[m] = *(const s16x8*)(buf + aoff + m * 1024);
#pragma unroll
        for (int n = 0; n < 4; ++n) bfr[n] = *(const s16x8*)(buf + boff + n * 1024);
#pragma unroll
        for (int m = 0; m < 4; ++m)
#pragma unroll
            for (int n = 0; n < 4; ++n)
                acc[m][n] = __builtin_amdgcn_mfma_f32_16x16x32_bf16(af[m], bfr[n], acc[m][n], 0, 0, 0);
        __syncthreads();
        cur ^= 1;
    }

    const float* be = bias + (long)e * Nn;

    if constexpr (!FUSE) {
        unsigned short (*h)[136] = (unsigned short (*)[136])smem;
#pragma unroll
        for (int n = 0; n < 4; ++n) {
            const int lc = 64 * wc + 16 * n + lr;
            const float bb = be[n0 + lc];
#pragma unroll
            for (int m = 0; m < 4; ++m) {
                const int rbase = 64 * wr + 16 * m + (l >> 4) * 4;
                f32x4 v = acc[m][n];
#pragma unroll
                for (int j = 0; j < 4; ++j) {
                    float xv = v[j] + bb;
                    if (relu) xv = fmaxf(xv, 0.0f);
                    h[rbase + j][lc] = f2bf(xv);
                }
            }
        }
        __syncthreads();
        unsigned short* oe = (unsigned short*)outp + (long)e * strideOe;
#pragma unroll
        for (int it = 0; it < 8; ++it) {
            const int row = (tid >> 4) + 16 * it;
            const int ch = tid & 15;
            s16x8 v = *(const s16x8*)&h[row][ch * 8];
            *(s16x8*)(oe + (long)(m0 + row) * Nn + n0 + ch * 8) = v;
        }
    } else {
        float* outf = (float*)outp;
        float (*h2)[132] = (float (*)[132])smem;
#pragma unroll
        for (int p2 = 0; p2 < 2; ++p2) {
            if (p2) __syncthreads();
            if (wr == p2) {
#pragma unroll
                for (int n = 0; n < 4; ++n) {
                    const int lc = 64 * wc + 16 * n + lr;
                    const float bb = be[n0 + lc];
#pragma unroll
                    for (int m = 0; m < 4; ++m) {
                        const int rloc = 16 * m + (l >> 4) * 4;
                        f32x4 v = acc[m][n];
#pragma unroll
                        for (int j = 0; j < 4; ++j) h2[rloc + j][lc] = v[j] + bb;
                    }
                }
            }
            __syncthreads();
#pragma unroll
            for (int it = 0; it < 8; ++it) {
                const int lin = it * 256 + tid;
                const int row = lin >> 5;
                const int c4 = (lin & 31) * 4;
                const long grow = (long)m0 + p2 * 64 + row;
                const float g = gate8[grow * 8];
                float* op = outf + grow * Nn + n0 + c4;
                float4 hv = *(const float4*)&h2[row][c4];
                float4 r;
                if (first) {
                    r = make_float4(g * hv.x, g * hv.y, g * hv.z, g * hv.w);
                } else {
                    float4 o0 = *(const float4*)op;
                    r = make_float4(o0.x + g * hv.x, o0.y + g * hv.y,
                                    o0.z + g * hv.z, o0.w + g * hv.w);
                }
                *(float4*)op = r;
            }
        }
    }
}

// ---------------- combine: out[n][c] = sum_e gate[n][e]*o_e[n][c] ----------------
__global__ __launch_bounds__(256) void combine_kernel(const unsigned short* __restrict__ o,
                                                      const float* __restrict__ gate,
                                                      float* __restrict__ out, int Nc) {
    const long t = (long)blockIdx.x * 256 + threadIdx.x;
    const int n = (int)(t >> 7);
    const int ch = (int)(t & 127) * 8;
    float g[8];
#pragma unroll
    for (int e = 0; e < 8; ++e) g[e] = gate[n * 8 + e];
    float a[8] = {};
#pragma unroll
    for (int e = 0; e < 8; ++e) {
        s16x8 v = *(const s16x8*)(o + (long)e * Nc * DOUT_ + (long)n * DOUT_ + ch);
        const float ge = g[e];
#pragma unroll
        for (int j = 0; j < 8; ++j) a[j] = fmaf(ge, bf2f((unsigned short)v[j]), a[j]);
    }
    float* op = out + (long)n * DOUT_ + ch;
    *(float4*)(op) = make_float4(a[0], a[1], a[2], a[3]);
    *(float4*)(op + 4) = make_float4(a[4], a[5], a[6], a[7]);
}

extern "C" void kernel_launch(void* const* d_in, const int* in_sizes, int n_in,
                              void* d_out, int out_size, void* d_ws, size_t ws_size,
                              hipStream_t stream) {
    const float* x   = (const float*)d_in[0];
    const float* gW  = (const float*)d_in[1];
    const float* gb  = (const float*)d_in[2];
    const float* W0  = (const float*)d_in[3];
    const float* b0  = (const float*)d_in[4];
    const float* W1  = (const float*)d_in[5];
    const float* b1  = (const float*)d_in[6];
    const float* Wf  = (const float*)d_in[7];
    const float* bfb = (const float*)d_in[8];
    float* out = (float*)d_out;
    char* ws = (char*)d_ws;

    unsigned short* xb = (unsigned short*)ws;                       // 16 MiB
    float* gate = (float*)(ws + (size_t)NTOK_ * DIN_ * 2);          // 256 KiB
    const size_t base = (size_t)NTOK_ * DIN_ * 2 + (size_t)NTOK_ * E_ * 4;

    const size_t wfull = (size_t)E_ * 2 * ((size_t)DIN_ * DH_ + (size_t)DH_ * DH_ + (size_t)DH_ * DOUT_);
    const size_t wexp = wfull / E_;

    int Nc = 0, batched = 0;
    if (ws_size > base + wfull) {
        const size_t rem = ws_size - base - wfull;
        for (int nc = 8192; nc >= 256; nc >>= 1)
            if ((size_t)nc * 65536 <= rem) { Nc = nc; batched = 1; break; }
    }
    if (!batched) {
        const size_t rem = (ws_size > base + wexp) ? ws_size - base - wexp : 0;
        for (int nc = 8192; nc >= 128; nc >>= 1)
            if ((size_t)nc * 8192 <= rem) { Nc = nc; break; }
        if (!Nc) Nc = 128;
    }
    const int nch = NTOK_ / Nc;

    cvt_f32_bf16<<<NTOK_ * DIN_ / 8 / 256, 256, 0, stream>>>(x, xb, (long)NTOK_ * DIN_ / 8);
    gate_kernel<<<NTOK_ / 4, 256, 0, stream>>>(x, gW, gb, gate);

    if (batched) {
        hipFuncSetAttribute(reinterpret_cast<const void*>(&moe_gemm256),
                            hipFuncAttributeMaxDynamicSharedMemorySize, 131072);
        unsigned short* W0b = (unsigned short*)(ws + base);
        unsigned short* W1b = W0b + (size_t)E_ * DIN_ * DH_;
        unsigned short* Wfb = W1b + (size_t)E_ * DH_ * DH_;
        unsigned short* h0  = Wfb + (size_t)E_ * DH_ * DOUT_;
        unsigned short* h1  = h0 + (size_t)E_ * Nc * DH_;
        tcvt_kernel<<<dim3(DH_ / 64, DIN_ / 64, E_), 256, 0, stream>>>(W0, W0b, DIN_, DH_);
        tcvt_kernel<<<dim3(DH_ / 64, DH_ / 64, E_), 256, 0, stream>>>(W1, W1b, DH_, DH_);
        tcvt_kernel<<<dim3(DOUT_ / 64, DH_ / 64, E_), 256, 0, stream>>>(Wf, Wfb, DH_, DOUT_);
        for (int c = 0; c < nch; ++c) {
            const long r0 = (long)c * Nc;
            moe_gemm256<<<dim3(DH_ / 256, Nc / 256, E_), 512, 131072, stream>>>(
                xb + r0 * DIN_, W0b, b0, h0, Nc, DH_, DIN_,
                0L, (long)DIN_ * DH_, (long)Nc * DH_, 1);
            moe_gemm256<<<dim3(DH_ / 256, Nc / 256, E_), 512, 131072, stream>>>(
                h0, W1b, b1, h1, Nc, DH_, DH_,
                (long)Nc * DH_, (long)DH_ * DH_, (long)Nc * DH_, 1);
            unsigned short* o = h0;
            moe_gemm256<<<dim3(DOUT_ / 256, Nc / 256, E_), 512, 131072, stream>>>(
                h1, Wfb, bfb, o, Nc, DOUT_, DH_,
                (long)Nc * DH_, (long)DH_ * DOUT_, (long)Nc * DOUT_, 0);
            combine_kernel<<<Nc / 2, 256, 0, stream>>>(o, gate + r0 * E_, out + r0 * DOUT_, Nc);
        }
    } else {
        unsigned short* W0s = (unsigned short*)(ws + base);
        unsigned short* W1s = W0s + (size_t)DIN_ * DH_;
        unsigned short* Wfs = W1s + (size_t)DH_ * DH_;
        unsigned short* h0s = Wfs + (size_t)DH_ * DOUT_;
        unsigned short* h1s = h0s + (size_t)Nc * DH_;
        for (int e = 0; e < E_; ++e) {
            tcvt_kernel<<<dim3(DH_ / 64, DIN_ / 64, 1), 256, 0, stream>>>(
                W0 + (size_t)e * DIN_ * DH_, W0s, DIN_, DH_);
            tcvt_kernel<<<dim3(DH_ / 64, DH_ / 64, 1), 256, 0, stream>>>(
                W1 + (size_t)e * DH_ * DH_, W1s, DH_, DH_);
            tcvt_kernel<<<dim3(DOUT_ / 64, DH_ / 64, 1), 256, 0, stream>>>(
                Wf + (size_t)e * DH_ * DOUT_, Wfs, DH_, DOUT_);
            for (int c = 0; c < nch; ++c) {
                const long r0 = (long)c * Nc;
                moe_gemm<0><<<dim3(DH_ / 128, Nc / 128, 1), 256, 0, stream>>>(
                    xb + r0 * DIN_, W0s, b0 + e * DH_, h0s, nullptr, Nc, DH_, DIN_,
                    0L, 0L, 0L, 1, 0);
                moe_gemm<0><<<dim3(DH_ / 128, Nc / 128, 1), 256, 0, stream>>>(
                    h0s, W1s, b1 + e * DH_, h1s, nullptr, Nc, DH_, DH_,
                    0L, 0L, 0L, 1, 0);
                moe_gemm<1><<<dim3(DOUT_ / 128, Nc / 128, 1), 256, 0, stream>>>(
                    h1s, Wfs, bfb + e * DOUT_, out + r0 * DOUT_, gate + r0 * E_ + e,
                    Nc, DOUT_, DH_, 0L, 0L, 0L, 0, (e == 0) ? 1 : 0);
            }
        }
    }
}

// Round 5
// 1125.679 us; speedup vs baseline: 1.3803x; 1.0167x over previous
//
#include <hip/hip_runtime.h>
#include <hip/hip_bf16.h>

// MoE dense: E=8, D_IN=1024, D_HID=2048, D_OUT=1024, N=8192.
// bf16 MFMA GEMMs; batched tier uses 256x256 8-phase template (T2+T3+T4+T5)
// with 8-barrier/iter schedule + one-phase-ahead fragment prefetch (race-fixed:
// post-VMW prefetch reads now follow a confirming barrier); per-expert
// fallback tier keeps the 128x128 m97 structure.

typedef short s16x8 __attribute__((ext_vector_type(8)));
typedef float f32x4 __attribute__((ext_vector_type(4)));

#define E_ 8
#define DIN_ 1024
#define DH_ 2048
#define DOUT_ 1024
#define NTOK_ 8192

__device__ __forceinline__ unsigned short f2bf(float x) {
    union { float f; unsigned u; } c; c.f = x;
    unsigned r = c.u + 0x7fffu + ((c.u >> 16) & 1u);   // RNE
    return (unsigned short)(r >> 16);
}
__device__ __forceinline__ float bf2f(unsigned short s) {
    union { unsigned u; float f; } c; c.u = ((unsigned)s) << 16;
    return c.f;
}
__device__ __forceinline__ void gload_lds16(const void* g, void* l) {
    __builtin_amdgcn_global_load_lds((const __attribute__((address_space(1))) void*)g,
                                     (__attribute__((address_space(3))) void*)l, 16, 0, 0);
}

// ---------------- fp32 -> bf16 elementwise (x) ----------------
__global__ __launch_bounds__(256) void cvt_f32_bf16(const float* __restrict__ in,
                                                    unsigned short* __restrict__ out,
                                                    long n8) {
    long i = (long)blockIdx.x * 256 + threadIdx.x;
    if (i >= n8) return;
    const float4* p = (const float4*)(in + i * 8);
    float4 a = p[0], b = p[1];
    s16x8 v;
    v[0] = (short)f2bf(a.x); v[1] = (short)f2bf(a.y);
    v[2] = (short)f2bf(a.z); v[3] = (short)f2bf(a.w);
    v[4] = (short)f2bf(b.x); v[5] = (short)f2bf(b.y);
    v[6] = (short)f2bf(b.z); v[7] = (short)f2bf(b.w);
    *(s16x8*)(out + i * 8) = v;
}

// ------------- transpose+convert: in [Z][K][Nn] fp32 -> out [Z][Nn][K] bf16 -------------
__global__ __launch_bounds__(256) void tcvt_kernel(const float* __restrict__ in,
                                                   unsigned short* __restrict__ out,
                                                   int K, int Nn) {
    __shared__ unsigned short t[64][72];
    const int e = blockIdx.z;
    const float* ie = in + (long)e * K * Nn;
    unsigned short* oe = out + (long)e * K * Nn;
    const int k0 = blockIdx.y * 64, n0 = blockIdx.x * 64;
    const int tid = threadIdx.x;
    const int c4 = (tid & 15) * 4;
#pragma unroll
    for (int i = 0; i < 4; ++i) {
        const int k = (tid >> 4) + 16 * i;
        float4 v = *(const float4*)(ie + (long)(k0 + k) * Nn + n0 + c4);
        t[c4 + 0][k] = f2bf(v.x);
        t[c4 + 1][k] = f2bf(v.y);
        t[c4 + 2][k] = f2bf(v.z);
        t[c4 + 3][k] = f2bf(v.w);
    }
    __syncthreads();
#pragma unroll
    for (int i = 0; i < 2; ++i) {
        const int idx = tid + 256 * i;
        const int rn = idx >> 3, ck = idx & 7;
        s16x8 v = *(const s16x8*)&t[rn][ck * 8];
        *(s16x8*)(oe + (long)(n0 + rn) * K + k0 + ck * 8) = v;
    }
}

// ---------------- gate: softmax(x @ gW + gb) , fp32 ----------------
__global__ __launch_bounds__(256) void gate_kernel(const float* __restrict__ x,
                                                   const float* __restrict__ gW,
                                                   const float* __restrict__ gb,
                                                   float* __restrict__ gate) {
    __shared__ float gws[8 * 1024];
    const int tid = threadIdx.x;
    for (int idx = tid; idx < 8 * 1024; idx += 256)
        gws[(idx & 7) * 1024 + (idx >> 3)] = gW[idx];
    __syncthreads();
    const int w = tid >> 6, l = tid & 63;
    const int n = blockIdx.x * 4 + w;
    const float* xr = x + (long)n * 1024;
    float acc[8] = {};
    for (int k = l; k < 1024; k += 64) {
        const float xv = xr[k];
#pragma unroll
        for (int e = 0; e < 8; ++e) acc[e] += xv * gws[e * 1024 + k];
    }
#pragma unroll
    for (int e = 0; e < 8; ++e)
        for (int off = 32; off > 0; off >>= 1) acc[e] += __shfl_xor(acc[e], off);
    if (l == 0) {
        float m = -1e30f;
#pragma unroll
        for (int e = 0; e < 8; ++e) { acc[e] += gb[e]; m = fmaxf(m, acc[e]); }
        float s = 0.f;
#pragma unroll
        for (int e = 0; e < 8; ++e) { acc[e] = __expf(acc[e] - m); s += acc[e]; }
        const float inv = 1.0f / s;
#pragma unroll
        for (int e = 0; e < 8; ++e) gate[n * 8 + e] = acc[e] * inv;
    }
}

// ================= 256x256 8-phase bf16 GEMM (batched tier) =================
// A [z][M][K], Bt [z][Nn][K] bf16 ; out bf16 [z][M][Nn] = act(A@Bt^T + bias)
// 512 thr = 8 waves (2Mx4N); BK=64; LDS 128KB = 2 K-tile dbuf (A 32K + B 32K).
// Swizzle: 16B chunk at phys slot s of row r holds logical chunk s^(r&7).
// Schedule (audited WAR/RAW, 8 barriers/iter): each block
// {BARR; lgkm0; MFMA; stage; prefetch-reads}; post-VMW prefetches at b4/b8
// are issued AFTER a confirming barrier (all waves' vmcnt drained).

#define BARR() asm volatile("s_barrier" ::: "memory")
#define LGKM0() do { asm volatile("s_waitcnt lgkmcnt(0)" ::: "memory"); \
                     __builtin_amdgcn_sched_barrier(0); } while (0)
#define VMW(n) do { asm volatile("s_waitcnt vmcnt(" #n ")" ::: "memory"); \
                    __builtin_amdgcn_sched_barrier(0); } while (0)

__global__ __launch_bounds__(512, 2) void moe_gemm256(const unsigned short* __restrict__ A,
                                                      const unsigned short* __restrict__ Bt,
                                                      const float* __restrict__ bias,
                                                      unsigned short* __restrict__ out,
                                                      int M, int Nn, int K,
                                                      long sAe, long sBe, long sOe, int relu) {
    extern __shared__ char smem[];
    const int tid = threadIdx.x;
    const int l = tid & 63, wid = tid >> 6;
    const int wr = wid >> 2, wc = wid & 3;
    const int e = blockIdx.z;
    // bijective XCD swizzle (m204) on the per-expert (x,y) grid
    const int gx = gridDim.x;
    int lin = blockIdx.x + gx * blockIdx.y;
    {
        const int nwg = gx * gridDim.y;
        const int q = nwg >> 3, r = nwg & 7;
        const int xcd = lin & 7, idx = lin >> 3;
        lin = (xcd < r ? xcd * (q + 1) : r * (q + 1) + (xcd - r) * q) + idx;
    }
    const int n0 = (lin % gx) * 256;
    const int m0 = (lin / gx) * 256;

    const unsigned short* Ae = A + (long)e * sAe;
    const unsigned short* Be = Bt + (long)e * sBe;

    // staging addresses: phys chunk (row, s=lane&7) <- logical c16 = s ^ (row&7)
    const int srow = wid * 8 + (l >> 3);
    const int sc8 = ((l & 7) ^ (l >> 3)) * 8;
    const unsigned short* pA = Ae + (long)(m0 + srow) * K + sc8;
    const unsigned short* pB = Be + (long)(n0 + srow) * K + sc8;
    const long kst64 = 64L * K;
    char* ldsW = smem + wid * 1024;

#define STAGE_A(buf, half, kt) do { \
        const unsigned short* s_ = pA + (long)(half) * 128 * K + (long)(kt) * 64; \
        char* d_ = ldsW + (buf) * 65536 + (half) * 16384; \
        gload_lds16(s_, d_); gload_lds16(s_ + kst64, d_ + 8192); } while (0)
#define STAGE_B(buf, half, kt) do { \
        const unsigned short* s_ = pB + (long)(half) * 128 * K + (long)(kt) * 64; \
        char* d_ = ldsW + (buf) * 65536 + 32768 + (half) * 16384; \
        gload_lds16(s_, d_); gload_lds16(s_ + kst64, d_ + 8192); } while (0)

    // ds_read fragment addressing
    const int arow = l & 15;
    const int aswz = ((l >> 4) ^ (l & 7)) << 4;
    const int aoffb = wr * 16384 + arow * 128;
    const int boffb = 32768 + wc * 8192 + arow * 128;

    f32x4 acc[8][4] = {};
    s16x8 af[4][2], bf0[2][2], bf1[2][2];

#define LDA(buf, mhalf) do { \
        const char* p_ = smem + (buf) * 65536 + aoffb + (mhalf) * 8192; \
        _Pragma("unroll") for (int mi_ = 0; mi_ < 4; ++mi_) \
        _Pragma("unroll") for (int kk_ = 0; kk_ < 2; ++kk_) \
            af[mi_][kk_] = *(const s16x8*)(p_ + mi_ * 2048 + (aswz ^ (kk_ << 6))); } while (0)
#define LDB(buf, nhalf, dst) do { \
        const char* p_ = smem + (buf) * 65536 + boffb + (nhalf) * 4096; \
        _Pragma("unroll") for (int ni_ = 0; ni_ < 2; ++ni_) \
        _Pragma("unroll") for (int kk_ = 0; kk_ < 2; ++kk_) \
            dst[ni_][kk_] = *(const s16x8*)(p_ + ni_ * 2048 + (aswz ^ (kk_ << 6))); } while (0)
#define MFMA8(mb, nb, bfr) do { __builtin_amdgcn_s_setprio(1); \
        _Pragma("unroll") for (int mi_ = 0; mi_ < 4; ++mi_) \
        _Pragma("unroll") for (int ni_ = 0; ni_ < 2; ++ni_) \
        _Pragma("unroll") for (int kk_ = 0; kk_ < 2; ++kk_) \
            acc[(mb) + mi_][(nb) + ni_] = __builtin_amdgcn_mfma_f32_16x16x32_bf16( \
                af[mi_][kk_], bfr[ni_][kk_], acc[(mb) + mi_][(nb) + ni_], 0, 0, 0); \
        __builtin_amdgcn_s_setprio(0); __builtin_amdgcn_sched_barrier(0); } while (0)

    const int nit = K >> 7;   // K/128, >=8 for all layers

    // prologue: X(kt0) full, then Y(kt1).B0, Y(kt1).A0; confirm; prefetch b1 frags
    STAGE_A(0, 0, 0); STAGE_A(0, 1, 0); STAGE_B(0, 0, 0); STAGE_B(0, 1, 0);
    STAGE_B(1, 0, 1); STAGE_A(1, 0, 1);
    VMW(4);
    BARR();
    LDA(0, 0); LDB(0, 0, bf0);

    for (int it = 0; it < nit; ++it) {
        const int ktY = 2 * it + 1;
        const int ktX2 = (it + 1 < nit) ? 2 * it + 2 : 0;
        const int ktY2 = (it + 1 < nit) ? 2 * it + 3 : 1;
        // b1 (follows post-VMW barrier of prev b8 / prologue)
        LGKM0(); MFMA8(0, 0, bf0);
        STAGE_A(1, 1, ktY);
        LDB(0, 1, bf1);
        // b2
        BARR(); LGKM0(); MFMA8(0, 2, bf1);
        STAGE_B(1, 1, ktY);
        LDA(0, 1);
        // b3
        BARR(); LGKM0(); MFMA8(4, 2, bf1);
        STAGE_B(0, 0, ktX2);
        // b4: VMW(4) drains this wave's Y stages; BARR confirms all waves;
        //     only then prefetch Y fragments
        BARR(); MFMA8(4, 0, bf0);
        STAGE_B(0, 1, ktX2);
        VMW(4);
        BARR();
        LDA(1, 0); LDB(1, 0, bf0);
        // b5
        LGKM0(); MFMA8(0, 0, bf0);
        STAGE_A(0, 0, ktX2);
        LDB(1, 1, bf1);
        // b6
        BARR(); LGKM0(); MFMA8(0, 2, bf1);
        STAGE_A(0, 1, ktX2);
        LDA(1, 1);
        // b7
        BARR(); LGKM0(); MFMA8(4, 2, bf1);
        STAGE_B(1, 0, ktY2);
        // b8: VMW(4) drains X' stages; BARR confirms; prefetch X' fragments
        BARR(); MFMA8(4, 0, bf0);
        STAGE_A(1, 0, ktY2);
        VMW(4);
        BARR();
        LDA(0, 0); LDB(0, 0, bf0);
    }
    LGKM0();
    VMW(0);
    BARR();   // drain everything before LDS reuse

    // epilogue: bias(+relu) -> bf16, two 128-row passes through LDS [128][272]
    unsigned short* oe = out + (long)e * sOe;
    const float* be = bias + (long)e * Nn;
    float bv[4];
#pragma unroll
    for (int ni = 0; ni < 4; ++ni) bv[ni] = be[n0 + 64 * wc + 16 * ni + arow];
    unsigned short (*h)[272] = (unsigned short (*)[272])smem;
#pragma unroll
    for (int p = 0; p < 2; ++p) {
        if (p) BARR();
        if (wr == p) {
#pragma unroll
            for (int mi = 0; mi < 8; ++mi)
#pragma unroll
                for (int ni = 0; ni < 4; ++ni) {
                    const int col = 64 * wc + 16 * ni + arow;
                    const int rl = 16 * mi + (l >> 4) * 4;
#pragma unroll
                    for (int j = 0; j < 4; ++j) {
                        float xv = acc[mi][ni][j] + bv[ni];
                        if (relu) xv = fmaxf(xv, 0.0f);
                        h[rl + j][col] = f2bf(xv);
                    }
                }
        }
        BARR();
#pragma unroll
        for (int i = 0; i < 8; ++i) {
            const int lin2 = i * 512 + tid;
            const int row = lin2 >> 5, ch = (lin2 & 31) * 8;
            s16x8 v = *(const s16x8*)&h[row][ch];
            *(s16x8*)(oe + (long)(m0 + 128 * p + row) * Nn + n0 + ch) = v;
        }
    }
#undef STAGE_A
#undef STAGE_B
#undef LDA
#undef LDB
#undef MFMA8
}

// ================= 128x128 GEMM (fallback tier) =================
// FUSE=0: out bf16 = act(A@Bt^T+bias); FUSE=1: out fp32 (+)= gate8 * (...)
template <int FUSE>
__global__ __launch_bounds__(256) void moe_gemm(const unsigned short* __restrict__ A,
                                                const unsigned short* __restrict__ Bt,
                                                const float* __restrict__ bias,
                                                void* __restrict__ outp,
                                                const float* __restrict__ gate8,
                                                int M, int Nn, int K,
                                                long strideAe, long strideBe, long strideOe,
                                                int relu, int first) {
    __shared__ __align__(16) char smem[34816];
    const int tid = threadIdx.x;
    const int w = tid >> 6, l = tid & 63;
    const int e = blockIdx.z;
    const int m0 = blockIdx.y * 128;
    const int n0 = blockIdx.x * 128;

    const unsigned short* Ae = A + (long)e * strideAe;
    const unsigned short* Be = Bt + (long)e * strideBe;

    const int srow = tid >> 2;
    const int scol = (tid & 3) * 8;
    const unsigned short* gA = Ae + (long)(m0 + srow) * K + scol;
    const unsigned short* gB = Be + (long)(n0 + srow) * K + scol;
    const long rstep = (long)64 * K;

    char* ldsAw = smem + w * 1024;
    char* ldsBw = smem + 8192 + w * 1024;

    const int wr = w >> 1, wc = w & 1;
    const int lr = l & 15;
    const int aoff = (64 * wr + lr) * 64 + (l >> 4) * 16;
    const int boff = 8192 + (64 * wc + lr) * 64 + (l >> 4) * 16;

    f32x4 acc[4][4] = {};
    const int nt = K >> 5;

    gload_lds16(gA, ldsAw);
    gload_lds16(gA + rstep, ldsAw + 4096);
    gload_lds16(gB, ldsBw);
    gload_lds16(gB + rstep, ldsBw + 4096);
    __syncthreads();

    int cur = 0;
    for (int t = 0; t < nt; ++t) {
        if (t + 1 < nt) {
            const int nb = (cur ^ 1) * 16384;
            const unsigned short* a = gA + (t + 1) * 32;
            const unsigned short* b = gB + (t + 1) * 32;
            gload_lds16(a, ldsAw + nb);
            gload_lds16(a + rstep, ldsAw + nb + 4096);
            gload_lds16(b, ldsBw + nb);
            gload_lds16(b + rstep, ldsBw + nb + 4096);
        }
        const char* buf = smem + cur * 16384;
        s16x8 af[4], bfr[4];
#pragma unroll
        for (int m = 0; m < 4; ++m) af[m] = *(const s16x8*)(buf + aoff + m * 1024);
#pragma unroll
        for (int n = 0; n < 4; ++n) bfr[n] = *(const s16x8*)(buf + boff + n * 1024);
#pragma unroll
        for (int m = 0; m < 4; ++m)
#pragma unroll
            for (int n = 0; n < 4; ++n)
                acc[m][n] = __builtin_amdgcn_mfma_f32_16x16x32_bf16(af[m], bfr[n], acc[m][n], 0, 0, 0);
        __syncthreads();
        cur ^= 1;
    }

    const float* be = bias + (long)e * Nn;

    if constexpr (!FUSE) {
        unsigned short (*h)[136] = (unsigned short (*)[136])smem;
#pragma unroll
        for (int n = 0; n < 4; ++n) {
            const int lc = 64 * wc + 16 * n + lr;
            const float bb = be[n0 + lc];
#pragma unroll
            for (int m = 0; m < 4; ++m) {
                const int rbase = 64 * wr + 16 * m + (l >> 4) * 4;
                f32x4 v = acc[m][n];
#pragma unroll
                for (int j = 0; j < 4; ++j) {
                    float xv = v[j] + bb;
                    if (relu) xv = fmaxf(xv, 0.0f);
                    h[rbase + j][lc] = f2bf(xv);
                }
            }
        }
        __syncthreads();
        unsigned short* oe = (unsigned short*)outp + (long)e * strideOe;
#pragma unroll
        for (int it = 0; it < 8; ++it) {
            const int row = (tid >> 4) + 16 * it;
            const int ch = tid & 15;
            s16x8 v = *(const s16x8*)&h[row][ch * 8];
            *(s16x8*)(oe + (long)(m0 + row) * Nn + n0 + ch * 8) = v;
        }
    } else {
        float* outf = (float*)outp;
        float (*h2)[132] = (float (*)[132])smem;
#pragma unroll
        for (int p2 = 0; p2 < 2; ++p2) {
            if (p2) __syncthreads();
            if (wr == p2) {
#pragma unroll
                for (int n = 0; n < 4; ++n) {
                    const int lc = 64 * wc + 16 * n + lr;
                    const float bb = be[n0 + lc];
#pragma unroll
                    for (int m = 0; m < 4; ++m) {
                        const int rloc = 16 * m + (l >> 4) * 4;
                        f32x4 v = acc[m][n];
#pragma unroll
                        for (int j = 0; j < 4; ++j) h2[rloc + j][lc] = v[j] + bb;
                    }
                }
            }
            __syncthreads();
#pragma unroll
            for (int it = 0; it < 8; ++it) {
                const int lin = it * 256 + tid;
                const int row = lin >> 5;
                const int c4 = (lin & 31) * 4;
                const long grow = (long)m0 + p2 * 64 + row;
                const float g = gate8[grow * 8];
                float* op = outf + grow * Nn + n0 + c4;
                float4 hv = *(const float4*)&h2[row][c4];
                float4 r;
                if (first) {
                    r = make_float4(g * hv.x, g * hv.y, g * hv.z, g * hv.w);
                } else {
                    float4 o0 = *(const float4*)op;
                    r = make_float4(o0.x + g * hv.x, o0.y + g * hv.y,
                                    o0.z + g * hv.z, o0.w + g * hv.w);
                }
                *(float4*)op = r;
            }
        }
    }
}

// ---------------- combine: out[n][c] = sum_e gate[n][e]*o_e[n][c] ----------------
__global__ __launch_bounds__(256) void combine_kernel(const unsigned short* __restrict__ o,
                                                      const float* __restrict__ gate,
                                                      float* __restrict__ out, int Nc) {
    const long t = (long)blockIdx.x * 256 + threadIdx.x;
    const int n = (int)(t >> 7);
    const int ch = (int)(t & 127) * 8;
    float g[8];
#pragma unroll
    for (int e = 0; e < 8; ++e) g[e] = gate[n * 8 + e];
    float a[8] = {};
#pragma unroll
    for (int e = 0; e < 8; ++e) {
        s16x8 v = *(const s16x8*)(o + (long)e * Nc * DOUT_ + (long)n * DOUT_ + ch);
        const float ge = g[e];
#pragma unroll
        for (int j = 0; j < 8; ++j) a[j] = fmaf(ge, bf2f((unsigned short)v[j]), a[j]);
    }
    float* op = out + (long)n * DOUT_ + ch;
    *(float4*)(op) = make_float4(a[0], a[1], a[2], a[3]);
    *(float4*)(op + 4) = make_float4(a[4], a[5], a[6], a[7]);
}

extern "C" void kernel_launch(void* const* d_in, const int* in_sizes, int n_in,
                              void* d_out, int out_size, void* d_ws, size_t ws_size,
                              hipStream_t stream) {
    const float* x   = (const float*)d_in[0];
    const float* gW  = (const float*)d_in[1];
    const float* gb  = (const float*)d_in[2];
    const float* W0  = (const float*)d_in[3];
    const float* b0  = (const float*)d_in[4];
    const float* W1  = (const float*)d_in[5];
    const float* b1  = (const float*)d_in[6];
    const float* Wf  = (const float*)d_in[7];
    const float* bfb = (const float*)d_in[8];
    float* out = (float*)d_out;
    char* ws = (char*)d_ws;

    unsigned short* xb = (unsigned short*)ws;                       // 16 MiB
    float* gate = (float*)(ws + (size_t)NTOK_ * DIN_ * 2);          // 256 KiB
    const size_t base = (size_t)NTOK_ * DIN_ * 2 + (size_t)NTOK_ * E_ * 4;

    const size_t wfull = (size_t)E_ * 2 * ((size_t)DIN_ * DH_ + (size_t)DH_ * DH_ + (size_t)DH_ * DOUT_);
    const size_t wexp = wfull / E_;

    int Nc = 0, batched = 0;
    if (ws_size > base + wfull) {
        const size_t rem = ws_size - base - wfull;
        for (int nc = 8192; nc >= 256; nc >>= 1)
            if ((size_t)nc * 65536 <= rem) { Nc = nc; batched = 1; break; }
    }
    if (!batched) {
        const size_t rem = (ws_size > base + wexp) ? ws_size - base - wexp : 0;
        for (int nc = 8192; nc >= 128; nc >>= 1)
            if ((size_t)nc * 8192 <= rem) { Nc = nc; break; }
        if (!Nc) Nc = 128;
    }
    const int nch = NTOK_ / Nc;

    cvt_f32_bf16<<<NTOK_ * DIN_ / 8 / 256, 256, 0, stream>>>(x, xb, (long)NTOK_ * DIN_ / 8);
    gate_kernel<<<NTOK_ / 4, 256, 0, stream>>>(x, gW, gb, gate);

    if (batched) {
        hipFuncSetAttribute(reinterpret_cast<const void*>(&moe_gemm256),
                            hipFuncAttributeMaxDynamicSharedMemorySize, 131072);
        unsigned short* W0b = (unsigned short*)(ws + base);
        unsigned short* W1b = W0b + (size_t)E_ * DIN_ * DH_;
        unsigned short* Wfb = W1b + (size_t)E_ * DH_ * DH_;
        unsigned short* h0  = Wfb + (size_t)E_ * DH_ * DOUT_;
        unsigned short* h1  = h0 + (size_t)E_ * Nc * DH_;
        tcvt_kernel<<<dim3(DH_ / 64, DIN_ / 64, E_), 256, 0, stream>>>(W0, W0b, DIN_, DH_);
        tcvt_kernel<<<dim3(DH_ / 64, DH_ / 64, E_), 256, 0, stream>>>(W1, W1b, DH_, DH_);
        tcvt_kernel<<<dim3(DOUT_ / 64, DH_ / 64, E_), 256, 0, stream>>>(Wf, Wfb, DH_, DOUT_);
        for (int c = 0; c < nch; ++c) {
            const long r0 = (long)c * Nc;
            moe_gemm256<<<dim3(DH_ / 256, Nc / 256, E_), 512, 131072, stream>>>(
                xb + r0 * DIN_, W0b, b0, h0, Nc, DH_, DIN_,
                0L, (long)DIN_ * DH_, (long)Nc * DH_, 1);
            moe_gemm256<<<dim3(DH_ / 256, Nc / 256, E_), 512, 131072, stream>>>(
                h0, W1b, b1, h1, Nc, DH_, DH_,
                (long)Nc * DH_, (long)DH_ * DH_, (long)Nc * DH_, 1);
            unsigned short* o = h0;
            moe_gemm256<<<dim3(DOUT_ / 256, Nc / 256, E_), 512, 131072, stream>>>(
                h1, Wfb, bfb, o, Nc, DOUT_, DH_,
                (long)Nc * DH_, (long)DH_ * DOUT_, (long)Nc * DOUT_, 0);
            combine_kernel<<<Nc / 2, 256, 0, stream>>>(o, gate + r0 * E_, out + r0 * DOUT_, Nc);
        }
    } else {
        unsigned short* W0s = (unsigned short*)(ws + base);
        unsigned short* W1s = W0s + (size_t)DIN_ * DH_;
        unsigned short* Wfs = W1s + (size_t)DH_ * DH_;
        unsigned short* h0s = Wfs + (size_t)DH_ * DOUT_;
        unsigned short* h1s = h0s + (size_t)Nc * DH_;
        for (int e = 0; e < E_; ++e) {
            tcvt_kernel<<<dim3(DH_ / 64, DIN_ / 64, 1), 256, 0, stream>>>(
                W0 + (size_t)e * DIN_ * DH_, W0s, DIN_, DH_);
            tcvt_kernel<<<dim3(DH_ / 64, DH_ / 64, 1), 256, 0, stream>>>(
                W1 + (size_t)e * DH_ * DH_, W1s, DH_, DH_);
            tcvt_kernel<<<dim3(DOUT_ / 64, DH_ / 64, 1), 256, 0, stream>>>(
                Wf + (size_t)e * DH_ * DOUT_, Wfs, DH_, DOUT_);
            for (int c = 0; c < nch; ++c) {
                const long r0 = (long)c * Nc;
                moe_gemm<0><<<dim3(DH_ / 128, Nc / 128, 1), 256, 0, stream>>>(
                    xb + r0 * DIN_, W0s, b0 + e * DH_, h0s, nullptr, Nc, DH_, DIN_,
                    0L, 0L, 0L, 1, 0);
                moe_gemm<0><<<dim3(DH_ / 128, Nc / 128, 1), 256, 0, stream>>>(
                    h0s, W1s, b1 + e * DH_, h1s, nullptr, Nc, DH_, DH_,
                    0L, 0L, 0L, 1, 0);
                moe_gemm<1><<<dim3(DOUT_ / 128, Nc / 128, 1), 256, 0, stream>>>(
                    h1s, Wfs, bfb + e * DOUT_, out + r0 * DOUT_, gate + r0 * E_ + e,
                    Nc, DOUT_, DH_, 0L, 0L, 0L, 0, (e == 0) ? 1 : 0);
            }
        }
    }
}